// Round 1
// baseline (535.357 us; speedup 1.0000x reference)
//
#include <hip/hip_runtime.h>

#define N_NODES 500000
#define N_EDGES 5000000
#define D 16

// --- Phase 1: scatter-add of neighbor features + degree count ---------------
// 16 threads per edge: thread (e, d) does agg[dst[e]][d] += x[src[e]][d].
// 16 consecutive lanes share one edge -> the x-row read is one 64B segment,
// and the 16 atomicAdds land in 16 distinct dwords of one agg cache line.
__global__ void sage_scatter(const float* __restrict__ x,
                             const int* __restrict__ esrc,
                             const int* __restrict__ edst,
                             float* __restrict__ agg,
                             float* __restrict__ cnt) {
    long long gid = (long long)blockIdx.x * blockDim.x + threadIdx.x;
    long long e = gid >> 4;
    int d = (int)(gid & 15);
    if (e >= N_EDGES) return;
    int s = esrc[e];
    int t = edst[e];
    atomicAdd(&agg[(long long)t * D + d], x[(long long)s * D + d]);
    if (d == 0) atomicAdd(&cnt[t], 1.0f);
}

// --- Phase 2: out[i] = (agg[i]/max(cnt,1)) @ W_l^T + b_l + x[i] @ W_r^T -----
// One thread per node. agg lives in d_out; we read the row into registers,
// compute, and overwrite the same row (thread-private, no hazard).
__global__ void sage_finalize(const float* __restrict__ x,
                              float* __restrict__ agg_out,
                              const float* __restrict__ cnt,
                              const float* __restrict__ W_l,
                              const float* __restrict__ b_l,
                              const float* __restrict__ W_r) {
    __shared__ float sWl[D * D];
    __shared__ float sWr[D * D];
    __shared__ float sb[D];
    int tid = threadIdx.x;
    if (tid < D * D) {
        sWl[tid] = W_l[tid];
        sWr[tid] = W_r[tid];
    }
    if (tid < D) sb[tid] = b_l[tid];
    __syncthreads();

    int i = blockIdx.x * blockDim.x + tid;
    if (i >= N_NODES) return;

    float inv = 1.0f / fmaxf(cnt[i], 1.0f);

    float m[D], xv[D];
    const float4* ap = (const float4*)(agg_out + (long long)i * D);
    const float4* xp = (const float4*)(x + (long long)i * D);
#pragma unroll
    for (int q = 0; q < 4; ++q) {
        float4 a = ap[q];
        float4 b = xp[q];
        m[4 * q + 0] = a.x * inv; m[4 * q + 1] = a.y * inv;
        m[4 * q + 2] = a.z * inv; m[4 * q + 3] = a.w * inv;
        xv[4 * q + 0] = b.x; xv[4 * q + 1] = b.y;
        xv[4 * q + 2] = b.z; xv[4 * q + 3] = b.w;
    }

    float o[D];
#pragma unroll
    for (int oo = 0; oo < D; ++oo) {
        float acc = sb[oo];
#pragma unroll
        for (int k = 0; k < D; ++k)
            acc += m[k] * sWl[oo * D + k] + xv[k] * sWr[oo * D + k];
        o[oo] = acc;
    }

    float4* op = (float4*)(agg_out + (long long)i * D);
#pragma unroll
    for (int q = 0; q < 4; ++q)
        op[q] = make_float4(o[4 * q + 0], o[4 * q + 1], o[4 * q + 2], o[4 * q + 3]);
}

extern "C" void kernel_launch(void* const* d_in, const int* in_sizes, int n_in,
                              void* d_out, int out_size, void* d_ws, size_t ws_size,
                              hipStream_t stream) {
    const float* x   = (const float*)d_in[0];
    const int*   ei  = (const int*)d_in[1];   // [2, N_EDGES]: row0 = src, row1 = dst
    const float* W_l = (const float*)d_in[2];
    const float* b_l = (const float*)d_in[3];
    const float* W_r = (const float*)d_in[4];

    float* agg_out = (float*)d_out;           // reused: accumulator, then final output
    float* cnt     = (float*)d_ws;            // N_NODES floats (2 MB)

    hipMemsetAsync(agg_out, 0, (size_t)N_NODES * D * sizeof(float), stream);
    hipMemsetAsync(cnt, 0, (size_t)N_NODES * sizeof(float), stream);

    const int block = 256;
    long long total = (long long)N_EDGES * D;                 // 80M threads
    unsigned grid1 = (unsigned)((total + block - 1) / block); // 312500 blocks
    sage_scatter<<<grid1, block, 0, stream>>>(x, ei, ei + N_EDGES, agg_out, cnt);

    unsigned grid2 = (N_NODES + block - 1) / block;
    sage_finalize<<<grid2, block, 0, stream>>>(x, agg_out, cnt, W_l, b_l, W_r);
}